// Round 1
// baseline (787.305 us; speedup 1.0000x reference)
//
#include <hip/hip_runtime.h>

// Problem constants (match reference)
#define Bn 8
#define Cn 64
#define Hn 128
#define Wn 128
#define On 64
#define K2n 9
#define HWn (Hn * Wn)          // 16384
#define OFFC (2 * K2n)         // 18

// ---------------------------------------------------------------------------
// Kernel A: offset 1x1 conv.  off[b, o, h, w] = sum_c x[b,c,h,w]*w_off[o,c] + b_off[o]
// One thread per pixel (b,h,w); w_off (18x64) staged in LDS, broadcast reads.
// ---------------------------------------------------------------------------
__global__ __launch_bounds__(256) void off_kernel(
        const float* __restrict__ x,
        const float* __restrict__ w_off,
        const float* __restrict__ b_off,
        float* __restrict__ off) {
    __shared__ float wl[OFFC * Cn];   // [o][c]
    __shared__ float bl[OFFC];
    const int tid = threadIdx.x;
    for (int i = tid; i < OFFC * Cn; i += 256) wl[i] = w_off[i];
    if (tid < OFFC) bl[tid] = b_off[tid];
    __syncthreads();

    const int idx = blockIdx.x * 256 + tid;   // grid exactly covers B*HW
    const int b  = idx >> 14;                 // / HW
    const int hw = idx & (HWn - 1);

    float acc[OFFC];
#pragma unroll
    for (int o = 0; o < OFFC; o++) acc[o] = bl[o];

    const float* xp = x + (size_t)b * (Cn * HWn) + hw;
    for (int c = 0; c < Cn; c++) {
        float xv = xp[(size_t)c * HWn];       // coalesced across threads
#pragma unroll
        for (int o = 0; o < OFFC; o++) acc[o] += xv * wl[o * Cn + c];  // LDS broadcast
    }

    float* op = off + (size_t)b * (OFFC * HWn) + hw;
#pragma unroll
    for (int o = 0; o < OFFC; o++) op[(size_t)o * HWn] = acc[o];       // coalesced
}

// ---------------------------------------------------------------------------
// Kernel B: fused bilinear sampling + 3x3 deformable conv contraction.
// One thread per output pixel (b,h,w), accumulating all 64 output channels.
// k outer (9 taps): stage weight[:, :, k] as wl[c][o] in LDS (16 KB),
// then loop c: 4 corner gathers -> bilinear s -> 64 FMAs (float4 LDS broadcast).
// ---------------------------------------------------------------------------
__global__ __launch_bounds__(256) void dcn_kernel(
        const float* __restrict__ x,
        const float* __restrict__ weight,
        const float* __restrict__ off,
        float* __restrict__ out) {
    __shared__ float wl[Cn * On];     // [c][o] for current k, 16 KB
    const int tid = threadIdx.x;
    const int idx = blockIdx.x * 256 + tid;
    const int b  = idx >> 14;
    const int hw = idx & (HWn - 1);
    const int h = hw >> 7;
    const int w = hw & (Wn - 1);

    const float* xb = x + (size_t)b * (Cn * HWn);
    const float* offp = off + (size_t)b * (OFFC * HWn) + hw;

    float acc[On];
#pragma unroll
    for (int o = 0; o < On; o++) acc[o] = 0.f;

    for (int k = 0; k < K2n; k++) {
        __syncthreads();              // protect previous iteration's wl reads
        // stage weight slice: wl[c*64+o] = weight[o*576 + c*9 + k]
        for (int i = tid; i < Cn * On; i += 256) {
            int c = i >> 6, o = i & 63;
            wl[i] = weight[o * (Cn * K2n) + c * K2n + k];
        }

        // bilinear state for this tap (matches reference semantics exactly)
        const float offy = offp[(size_t)(2 * k) * HWn];
        const float offx = offp[(size_t)(2 * k + 1) * HWn];
        const int kh = k / 3, kw = k % 3;
        const float py = (float)(h - 1 + kh) + offy;
        const float px = (float)(w - 1 + kw) + offx;
        const float y0f = floorf(py), x0f = floorf(px);
        const float wy1 = py - y0f, wx1 = px - x0f;
        const float wy0 = 1.f - wy1, wx0 = 1.f - wx1;
        const int y0 = (int)y0f, x0 = (int)x0f;
        const int y1 = y0 + 1,  x1 = x0 + 1;
        const bool vy0 = (y0 >= 0) && (y0 < Hn);
        const bool vy1 = (y1 >= 0) && (y1 < Hn);
        const bool vx0 = (x0 >= 0) && (x0 < Wn);
        const bool vx1 = (x1 >= 0) && (x1 < Wn);
        const int yc0 = min(max(y0, 0), Hn - 1), yc1 = min(max(y1, 0), Hn - 1);
        const int xc0 = min(max(x0, 0), Wn - 1), xc1 = min(max(x1, 0), Wn - 1);
        const float w00 = (vy0 && vx0) ? wy0 * wx0 : 0.f;
        const float w01 = (vy0 && vx1) ? wy0 * wx1 : 0.f;
        const float w10 = (vy1 && vx0) ? wy1 * wx0 : 0.f;
        const float w11 = (vy1 && vx1) ? wy1 * wx1 : 0.f;
        const int a00 = yc0 * Wn + xc0, a01 = yc0 * Wn + xc1;
        const int a10 = yc1 * Wn + xc0, a11 = yc1 * Wn + xc1;

        __syncthreads();              // wl ready

        const float4* wl4 = (const float4*)wl;
#pragma unroll 2
        for (int c = 0; c < Cn; c++) {
            const float* xc = xb + (size_t)c * HWn;
            const float s = w00 * xc[a00] + w01 * xc[a01]
                          + w10 * xc[a10] + w11 * xc[a11];
#pragma unroll
            for (int o4 = 0; o4 < On / 4; o4++) {
                float4 wv = wl4[c * (On / 4) + o4];    // wave-uniform broadcast
                acc[o4 * 4 + 0] += s * wv.x;
                acc[o4 * 4 + 1] += s * wv.y;
                acc[o4 * 4 + 2] += s * wv.z;
                acc[o4 * 4 + 3] += s * wv.w;
            }
        }
    }

    float* op = out + (size_t)b * (On * HWn) + hw;
#pragma unroll
    for (int o = 0; o < On; o++) op[(size_t)o * HWn] = acc[o];   // coalesced
}

// ---------------------------------------------------------------------------
extern "C" void kernel_launch(void* const* d_in, const int* in_sizes, int n_in,
                              void* d_out, int out_size, void* d_ws, size_t ws_size,
                              hipStream_t stream) {
    const float* x      = (const float*)d_in[0];   // (8,64,128,128)
    const float* weight = (const float*)d_in[1];   // (64,64,3,3)
    const float* w_off  = (const float*)d_in[2];   // (18,64)
    const float* b_off  = (const float*)d_in[3];   // (18,)
    float* out = (float*)d_out;                    // (8,64,128,128)
    float* off = (float*)d_ws;                     // (8,18,128,128) scratch, 9.4 MB

    const int npix = Bn * HWn;                     // 131072
    off_kernel<<<npix / 256, 256, 0, stream>>>(x, w_off, b_off, off);
    dcn_kernel<<<npix / 256, 256, 0, stream>>>(x, weight, off, out);
}

// Round 2
// 354.628 us; speedup vs baseline: 2.2201x; 2.2201x over previous
//
#include <hip/hip_runtime.h>

// Problem constants
#define Bn 8
#define Cn 64
#define Hn 128
#define Wn 128
#define On 64
#define K2n 9
#define HWn (Hn * Wn)          // 16384
#define OFFC 18                // 2*K2
#define APAD 72                // LDS row stride in bf16 (64 + 8 pad -> kills 16-way conflicts)

typedef short bf16x8 __attribute__((ext_vector_type(8)));
typedef float f32x4  __attribute__((ext_vector_type(4)));

__device__ __forceinline__ unsigned int f2bf(float f) {
    // round-to-nearest-even fp32 -> bf16
    unsigned int u = __float_as_uint(f);
    return (u + 0x7FFFu + ((u >> 16) & 1u)) >> 16;
}

// ---------------------------------------------------------------------------
// Pre-kernel: repack weight (O,C,3,3) fp32 -> wt[k][o][c] bf16 so the main
// kernel's B-tile staging is fully coalesced 16B loads.
// ---------------------------------------------------------------------------
__global__ __launch_bounds__(256) void wconv_kernel(
        const float* __restrict__ w, unsigned short* __restrict__ wt) {
    int i = blockIdx.x * 256 + threadIdx.x;      // 9*64*64 = 36864 total
    if (i < K2n * On * Cn) {
        int c = i & 63;
        int o = (i >> 6) & 63;
        int k = i >> 12;
        wt[i] = (unsigned short)f2bf(w[o * (Cn * K2n) + c * K2n + k]);
    }
}

// ---------------------------------------------------------------------------
// Fused kernel: per block of 64 consecutive pixels (one row segment):
//   phase 0: offset 1x1 conv (fp32) for 18 offset channels -> LDS
//   per tap k (9): sample 64px x 64c bilinear -> bf16 A-tile in LDS,
//                  stage bf16 B-tile (weights for tap k),
//                  4 waves x 8 mfma_f32_16x16x32_bf16 accumulate 64px x 64o.
// ---------------------------------------------------------------------------
__global__ __launch_bounds__(256) void dcn_mfma_kernel(
        const float* __restrict__ x,
        const unsigned short* __restrict__ wt,   // bf16 [k][o][c]
        const float* __restrict__ w_off,
        const float* __restrict__ b_off,
        float* __restrict__ out) {
    __shared__ unsigned short Al[64 * APAD];     // A-tile: [pix][c], 9216 B
    __shared__ unsigned short Bl[64 * APAD];     // B-tile: [o][c],   9216 B
    __shared__ float offl[OFFC * 64];            // offsets [o18][pix], 4608 B
    __shared__ float wofl[OFFC * Cn];            // w_off staged,      4608 B

    const int tid = threadIdx.x;
    // XCD swizzle: blocks with bid%8==x cover image b=x -> per-XCD L2 holds x[b]
    const int bid = blockIdx.x;
    const int logical = ((bid & 7) << 8) | (bid >> 3);   // 2048 blocks
    const int b   = logical >> 8;
    const int hw0 = (logical & 255) << 6;                // 64-pixel row segment
    const int h   = hw0 >> 7;
    const int w0  = hw0 & 127;

    const int pix = tid & 63;
    const int cq  = tid >> 6;

    const float* xb = x + (size_t)b * (Cn * HWn);

    // ---- phase 0: offset conv --------------------------------------------
    for (int i = tid; i < OFFC * Cn; i += 256) wofl[i] = w_off[i];
    __syncthreads();
    {
        // thread (pix, cq): offset channels o in [cq*5, min(cq*5+5,18))
        const int o0 = cq * 5;
        const int o1 = min(o0 + 5, OFFC);
        float acc[5];
#pragma unroll
        for (int j = 0; j < 5; j++) acc[j] = 0.f;
        const float* xp = xb + hw0 + pix;
        for (int c = 0; c < Cn; c++) {
            float xv = xp[(size_t)c * HWn];       // coalesced across lanes
#pragma unroll
            for (int j = 0; j < 5; j++)
                if (o0 + j < o1) acc[j] += xv * wofl[(o0 + j) * Cn + c];
        }
#pragma unroll
        for (int j = 0; j < 5; j++)
            if (o0 + j < o1) offl[(o0 + j) * 64 + pix] = acc[j] + b_off[o0 + j];
    }
    __syncthreads();

    // ---- main: 9 taps ----------------------------------------------------
    f32x4 acc[4];
#pragma unroll
    for (int t = 0; t < 4; t++) acc[t] = (f32x4){0.f, 0.f, 0.f, 0.f};

    const int lane = tid & 63;
    const int wv   = tid >> 6;                         // wave id: M-strip
    const int arow = ((wv << 4) | (lane & 15)) * APAD; // A row (pixel) for mfma
    const int koff = (lane >> 4) << 3;                 // k-offset within K=32

    for (int k = 0; k < K2n; k++) {
        __syncthreads();   // previous tap's mfma reads done before overwrite

        // stage B-tile: Bl[o][c] <- wt[k][o][c], 16 bf16 per thread, coalesced
        {
            const uint4* src = (const uint4*)(wt + (size_t)k * (On * Cn)) + tid * 2;
            uint4* dst = (uint4*)&Bl[(tid >> 2) * APAD + ((tid & 3) << 4)];
            dst[0] = src[0];
            dst[1] = src[1];
        }

        // sample A-tile: thread (pix, cq) computes s for c = cq*16 .. +16
        {
            const float offy = offl[(2 * k) * 64 + pix];
            const float offx = offl[(2 * k + 1) * 64 + pix];
            const int kh = k / 3, kw = k - kh * 3;
            const float py = (float)(h - 1 + kh) + offy;
            const float px = (float)(w0 + pix - 1 + kw) + offx;
            const float y0f = floorf(py), x0f = floorf(px);
            const float wy1 = py - y0f, wx1 = px - x0f;
            const float wy0 = 1.f - wy1, wx0 = 1.f - wx1;
            const int y0 = (int)y0f, x0i = (int)x0f;
            const int y1 = y0 + 1,  x1 = x0i + 1;
            const bool vy0 = (y0 >= 0) && (y0 < Hn);
            const bool vy1 = (y1 >= 0) && (y1 < Hn);
            const bool vx0 = (x0i >= 0) && (x0i < Wn);
            const bool vx1 = (x1 >= 0) && (x1 < Wn);
            const int yc0 = min(max(y0, 0), Hn - 1), yc1 = min(max(y1, 0), Hn - 1);
            const int xc0 = min(max(x0i, 0), Wn - 1), xc1 = min(max(x1, 0), Wn - 1);
            const float w00 = (vy0 && vx0) ? wy0 * wx0 : 0.f;
            const float w01 = (vy0 && vx1) ? wy0 * wx1 : 0.f;
            const float w10 = (vy1 && vx0) ? wy1 * wx0 : 0.f;
            const float w11 = (vy1 && vx1) ? wy1 * wx1 : 0.f;
            const int a00 = yc0 * Wn + xc0, a01 = yc0 * Wn + xc1;
            const int a10 = yc1 * Wn + xc0, a11 = yc1 * Wn + xc1;

            const float* xcp = xb + (size_t)(cq << 4) * HWn;
            unsigned int pk[8];
#pragma unroll
            for (int i = 0; i < 8; i++) {
                float s0 = w00 * xcp[a00] + w01 * xcp[a01]
                         + w10 * xcp[a10] + w11 * xcp[a11];
                xcp += HWn;
                float s1 = w00 * xcp[a00] + w01 * xcp[a01]
                         + w10 * xcp[a10] + w11 * xcp[a11];
                xcp += HWn;
                pk[i] = f2bf(s0) | (f2bf(s1) << 16);
            }
            uint4* dst = (uint4*)&Al[pix * APAD + (cq << 4)];
            dst[0] = make_uint4(pk[0], pk[1], pk[2], pk[3]);
            dst[1] = make_uint4(pk[4], pk[5], pk[6], pk[7]);
        }
        __syncthreads();

        // mfma: wave wv computes pixels [wv*16, wv*16+16) x all 64 o
#pragma unroll
        for (int ks = 0; ks < 64; ks += 32) {
            bf16x8 af = *(bf16x8*)&Al[arow + ks + koff];
#pragma unroll
            for (int t = 0; t < 4; t++) {
                bf16x8 bfr = *(bf16x8*)&Bl[(((t << 4) | (lane & 15)) * APAD) + ks + koff];
                acc[t] = __builtin_amdgcn_mfma_f32_16x16x32_bf16(af, bfr, acc[t], 0, 0, 0);
            }
        }
    }

    // ---- epilogue: C/D layout col(=o)=lane&15, row(=px)=(lane>>4)*4+r ----
    const int orow = (lane >> 4) << 2;
    float* ob = out + (size_t)b * (On * HWn) + hw0;
#pragma unroll
    for (int t = 0; t < 4; t++) {
        const int o = (t << 4) | (lane & 15);
        const int prow = (wv << 4) + orow;
#pragma unroll
        for (int r = 0; r < 4; r++) {
            ob[(size_t)o * HWn + prow + r] = acc[t][r];
        }
    }
}

// ---------------------------------------------------------------------------
extern "C" void kernel_launch(void* const* d_in, const int* in_sizes, int n_in,
                              void* d_out, int out_size, void* d_ws, size_t ws_size,
                              hipStream_t stream) {
    const float* x      = (const float*)d_in[0];   // (8,64,128,128)
    const float* weight = (const float*)d_in[1];   // (64,64,3,3)
    const float* w_off  = (const float*)d_in[2];   // (18,64)
    const float* b_off  = (const float*)d_in[3];   // (18,)
    float* out = (float*)d_out;                    // (8,64,128,128)
    unsigned short* wt = (unsigned short*)d_ws;    // bf16 [9][64][64], 73728 B

    wconv_kernel<<<(K2n * On * Cn + 255) / 256, 256, 0, stream>>>(weight, wt);
    dcn_mfma_kernel<<<2048, 256, 0, stream>>>(x, wt, w_off, b_off, out);
}